// Round 6
// baseline (308.548 us; speedup 1.0000x reference)
//
#include <hip/hip_runtime.h>

#define BB 8
#define TT 4096
#define FF 481
#define NF 96
#define FS 5

#define N_FILT (BB * TT * NF)          // 3,145,728 filter outputs
#define N_HI   (BB * TT * (FF - NF))   // 12,615,680 pairs to copy

#define FBLK 3072
#define FTH  (FBLK * 256)              // 786,432 threads; N_FILT / FTH == 4 exactly
#define CBLK 4096

__global__ __launch_bounds__(256) void df_filter(
    const float2* __restrict__ spec,   // (B,1,T,F) complex pairs
    const float2* __restrict__ coefs,  // (B,FS,T,NF) complex pairs
    float2* __restrict__ out)          // (B,1,T,F) complex pairs
{
    const unsigned base = blockIdx.x * 256u + threadIdx.x;

#pragma unroll
    for (int k = 0; k < 4; ++k) {
        const unsigned n  = base + (unsigned)k * (unsigned)FTH;
        const unsigned f  = n % (unsigned)NF;
        const unsigned bt = n / (unsigned)NF;       // b*T + t
        const unsigned t  = bt & (TT - 1u);
        const unsigned b  = bt >> 12;

        float accx = 0.f, accy = 0.f;
#pragma unroll
        for (int i = 0; i < FS; ++i) {
            const int ts = (int)t + i - (FS - 1);
            if (ts < 0) continue;
            const float2 s = spec[(b * TT + (unsigned)ts) * FF + f];
            const float2 c = coefs[((b * FS + (unsigned)i) * TT + t) * NF + f];
            accx = fmaf(s.x, c.x, accx);
            accx = fmaf(-s.y, c.y, accx);
            accy = fmaf(s.x, c.y, accy);
            accy = fmaf(s.y, c.x, accy);
        }
        float2 r; r.x = accx; r.y = accy;
        out[bt * FF + f] = r;
    }
}

__global__ __launch_bounds__(256) void df_copy(
    const float2* __restrict__ spec,
    float2* __restrict__ out)
{
    const unsigned stride = CBLK * 256u;
    unsigned n = blockIdx.x * 256u + threadIdx.x;

    while (n + 3u * stride < (unsigned)N_HI) {
        const unsigned n1 = n + stride;
        const unsigned n2 = n + 2u * stride;
        const unsigned n3 = n + 3u * stride;
        const unsigned i0 = (n  / 385u) * (unsigned)FF + (unsigned)NF + n  % 385u;
        const unsigned i1 = (n1 / 385u) * (unsigned)FF + (unsigned)NF + n1 % 385u;
        const unsigned i2 = (n2 / 385u) * (unsigned)FF + (unsigned)NF + n2 % 385u;
        const unsigned i3 = (n3 / 385u) * (unsigned)FF + (unsigned)NF + n3 % 385u;
        const float2 v0 = spec[i0];
        const float2 v1 = spec[i1];
        const float2 v2 = spec[i2];
        const float2 v3 = spec[i3];
        out[i0] = v0;
        out[i1] = v1;
        out[i2] = v2;
        out[i3] = v3;
        n += 4u * stride;
    }
    for (; n < (unsigned)N_HI; n += stride) {
        const unsigned i = (n / 385u) * (unsigned)FF + (unsigned)NF + n % 385u;
        out[i] = spec[i];
    }
}

extern "C" void kernel_launch(void* const* d_in, const int* in_sizes, int n_in,
                              void* d_out, int out_size, void* d_ws, size_t ws_size,
                              hipStream_t stream) {
    const float2* spec  = (const float2*)d_in[0];
    const float2* coefs = (const float2*)d_in[1];
    float2* out = (float2*)d_out;

    df_filter<<<dim3(FBLK), dim3(256), 0, stream>>>(spec, coefs, out);
    df_copy<<<dim3(CBLK), dim3(256), 0, stream>>>(spec, out);
}